// Round 1
// baseline (981.601 us; speedup 1.0000x reference)
//
#include <hip/hip_runtime.h>

#define N_NODES 100000
#define N_EDGES 1600000
#define D 48
#define DOUT 16

// ---------------- CSR build ----------------

__global__ __launch_bounds__(256) void hist_kernel(const int* __restrict__ dst,
                                                   int* __restrict__ cnt, int e) {
    int i = blockIdx.x * 256 + threadIdx.x;
    if (i < e) atomicAdd(&cnt[dst[i] + 1], 1);
}

// chunk = 2048 elements per block (256 threads x 8), inclusive scan in place
__global__ __launch_bounds__(256) void scan_partial(int* __restrict__ data,
                                                    int* __restrict__ bsums, int n) {
    __shared__ int sTot[256];
    int t = threadIdx.x;
    int base = blockIdx.x * 2048 + t * 8;
    int v[8];
    int s = 0;
#pragma unroll
    for (int i = 0; i < 8; ++i) {
        int idx = base + i;
        int x = (idx < n) ? data[idx] : 0;
        s += x;
        v[i] = s;
    }
    sTot[t] = s;
    __syncthreads();
    for (int off = 1; off < 256; off <<= 1) {
        int add = 0;
        if (t >= off) add = sTot[t - off];
        __syncthreads();
        if (t >= off) sTot[t] += add;
        __syncthreads();
    }
    int excl = (t > 0) ? sTot[t - 1] : 0;
#pragma unroll
    for (int i = 0; i < 8; ++i) {
        int idx = base + i;
        if (idx < n) data[idx] = v[i] + excl;
    }
    if (t == 255) bsums[blockIdx.x] = sTot[255];
}

__global__ void scan_sums(int* bsums, int nb) {
    if (threadIdx.x == 0 && blockIdx.x == 0) {
        int s = 0;
        for (int i = 0; i < nb; ++i) { s += bsums[i]; bsums[i] = s; }
    }
}

__global__ __launch_bounds__(256) void scan_add(int* __restrict__ data,
                                                const int* __restrict__ bsums, int n) {
    int b = blockIdx.x;
    if (b == 0) return;
    int base = b * 2048 + threadIdx.x * 8;
    int add = bsums[b - 1];
#pragma unroll
    for (int i = 0; i < 8; ++i) {
        int idx = base + i;
        if (idx < n) data[idx] += add;
    }
}

__global__ __launch_bounds__(256) void copy_starts(const int* __restrict__ rowptr,
                                                   int* __restrict__ cursor, int n) {
    int i = blockIdx.x * 256 + threadIdx.x;
    if (i < n) cursor[i] = rowptr[i];
}

__global__ __launch_bounds__(256) void fill_csr(const int* __restrict__ src,
                                                const int* __restrict__ dst,
                                                int* __restrict__ cursor,
                                                int* __restrict__ col, int e) {
    int i = blockIdx.x * 256 + threadIdx.x;
    if (i < e) {
        int d = dst[i];
        int pos = atomicAdd(&cursor[d], 1);
        col[pos] = src[i];
    }
}

// ---------------- aggregation: one wave per node, lane = feature ----------------

__global__ __launch_bounds__(256) void aggregate48(const float* __restrict__ h,
                                                   const int* __restrict__ rowptr,
                                                   const int* __restrict__ col,
                                                   float* __restrict__ out, int n) {
    int wave = (blockIdx.x * 256 + threadIdx.x) >> 6;
    int lane = threadIdx.x & 63;
    if (wave >= n) return;
    int start = rowptr[wave];
    int end = rowptr[wave + 1];
    if (lane < D) {
        float acc = 0.f;
        for (int e = start; e < end; ++e) {
            int s = col[e];  // uniform across the wave -> broadcast
            acc += h[s * D + lane];
        }
        out[wave * D + lane] = acc;
    }
}

// ---------------- fused (in [+agg]) @ W + b, optional ReLU ----------------
// W is row-major [48][M], like the reference (din, dout).

template <int M, bool RELU, bool ADD_AGG>
__global__ __launch_bounds__(256) void gemm48(const float* __restrict__ in,
                                              const float* __restrict__ agg,
                                              const float* __restrict__ W,
                                              const float* __restrict__ bias,
                                              float* __restrict__ out, int n) {
    constexpr int BN = 32;  // nodes per block
    __shared__ float sIn[BN][D];
    __shared__ float sW[D * M];
    __shared__ float sB[M];
    int tid = threadIdx.x;
    int n0 = blockIdx.x * BN;

    for (int i = tid; i < D * M; i += 256) sW[i] = W[i];
    if (tid < M) sB[tid] = bias[tid];
    for (int i = tid; i < BN * D; i += 256) {
        int nl = i / D, k = i % D;
        int node = n0 + nl;
        float v = 0.f;
        if (node < n) {
            v = in[node * D + k];
            if (ADD_AGG) v += agg[node * D + k];
        }
        sIn[nl][k] = v;
    }
    __syncthreads();

    for (int o = tid; o < BN * M; o += 256) {
        int nl = o / M, j = o % M;
        int node = n0 + nl;
        if (node >= n) continue;
        float acc = sB[j];
#pragma unroll
        for (int k = 0; k < D; ++k) acc += sIn[nl][k] * sW[k * M + j];
        if (RELU) acc = fmaxf(acc, 0.f);
        out[node * M + j] = acc;
    }
}

// ---------------- launch ----------------

extern "C" void kernel_launch(void* const* d_in, const int* in_sizes, int n_in,
                              void* d_out, int out_size, void* d_ws, size_t ws_size,
                              hipStream_t stream) {
    const int n = N_NODES, e = N_EDGES;
    const float* x = (const float*)d_in[0];
    const int* ei = (const int*)d_in[1];
    const int* src = ei;
    const int* dst = ei + e;
    const float* w11 = (const float*)d_in[2];
    const float* b11 = (const float*)d_in[3];
    const float* w12 = (const float*)d_in[4];
    const float* b12 = (const float*)d_in[5];
    const float* w21 = (const float*)d_in[6];
    const float* b21 = (const float*)d_in[7];
    const float* w22 = (const float*)d_in[8];
    const float* b22 = (const float*)d_in[9];
    const float* w31 = (const float*)d_in[10];
    const float* b31 = (const float*)d_in[11];
    const float* w32 = (const float*)d_in[12];
    const float* b32 = (const float*)d_in[13];
    const float* wf1 = (const float*)d_in[14];
    const float* bf1 = (const float*)d_in[15];
    const float* wf2 = (const float*)d_in[16];
    const float* bf2 = (const float*)d_in[17];
    float* out = (float*)d_out;

    // workspace layout
    float* A = (float*)d_ws;            // N*48
    float* B = A + (size_t)n * D;       // N*48
    float* T = B + (size_t)n * D;       // N*48
    int* rowptr = (int*)(T + (size_t)n * D);  // N+1
    int* cursor = rowptr + (n + 1);           // N
    int* colidx = cursor + n;                 // E
    int* bsums = colidx + e;                  // 64
    size_t needed = (size_t)((char*)(bsums + 64) - (char*)d_ws);
    if (needed > ws_size) return;  // leaves poison -> deterministic mismatch, no fault

    // ---- CSR build (once; edges constant across layers) ----
    hipMemsetAsync(rowptr, 0, (n + 1) * sizeof(int), stream);
    hist_kernel<<<(e + 255) / 256, 256, 0, stream>>>(dst, rowptr, e);
    int nb = (n + 1 + 2047) / 2048;  // 49
    scan_partial<<<nb, 256, 0, stream>>>(rowptr, bsums, n + 1);
    scan_sums<<<1, 64, 0, stream>>>(bsums, nb);
    scan_add<<<nb, 256, 0, stream>>>(rowptr, bsums, n + 1);
    copy_starts<<<(n + 255) / 256, 256, 0, stream>>>(rowptr, cursor, n);
    fill_csr<<<(e + 255) / 256, 256, 0, stream>>>(src, dst, cursor, colidx, e);

    int gAgg = (n + 3) / 4;     // 4 nodes (waves) per block
    int gGemm = (n + 31) / 32;  // 32 nodes per block

    // ---- conv1: in = x ----
    aggregate48<<<gAgg, 256, 0, stream>>>(x, rowptr, colidx, A, n);
    gemm48<D, true, true><<<gGemm, 256, 0, stream>>>(x, A, w11, b11, T, n);
    gemm48<D, true, false><<<gGemm, 256, 0, stream>>>(T, nullptr, w12, b12, A, n);
    // ---- conv2: in = A ----
    aggregate48<<<gAgg, 256, 0, stream>>>(A, rowptr, colidx, B, n);
    gemm48<D, true, true><<<gGemm, 256, 0, stream>>>(A, B, w21, b21, T, n);
    gemm48<D, true, false><<<gGemm, 256, 0, stream>>>(T, nullptr, w22, b22, A, n);
    // ---- conv3: in = A ----
    aggregate48<<<gAgg, 256, 0, stream>>>(A, rowptr, colidx, B, n);
    gemm48<D, true, true><<<gGemm, 256, 0, stream>>>(A, B, w31, b31, T, n);
    gemm48<D, true, false><<<gGemm, 256, 0, stream>>>(T, nullptr, w32, b32, A, n);
    // ---- head ----
    gemm48<D, true, false><<<gGemm, 256, 0, stream>>>(A, nullptr, wf1, bf1, T, n);
    gemm48<DOUT, false, false><<<gGemm, 256, 0, stream>>>(T, nullptr, wf2, bf2, out, n);
}